// Round 1
// baseline (5055.121 us; speedup 1.0000x reference)
//
#include <hip/hip_runtime.h>

// Problem constants (from reference): x [16,2048,512] -> N=32768 rows, C=512.
// codebooks [8,1024,512]. Output: quant_sum [N*C] fp32 + 1 scalar loss.
#define N_ROWS 32768
#define C_DIM  512
#define K_CODES 1024
#define Q_STAGES 8

// GEMM tile
#define BM 64
#define BN 128
#define BK 32
#define PAD 4
#define NCOLB (K_CODES / BN)   // 8 partial argmins per row

// Workspace layout (bytes)
#define ZE_OFF    0ull                                   // N*C*4 = 67108864
#define ZE2_OFF   67108864ull                            // N*4
#define C2_OFF    67239936ull                            // Q*K*4
#define PMIN_OFF  67272704ull                            // N*8*4
#define PIDX_OFF  68321280ull                            // N*8*4
#define LOSS_OFF  69369856ull                            // 8 floats

// -------- row sum-of-squares: one wave per row of 512 floats --------
__global__ __launch_bounds__(256) void rowsq_kernel(
    const float* __restrict__ src, float* __restrict__ dst, int nrows)
{
    int wave = (blockIdx.x * blockDim.x + threadIdx.x) >> 6;
    int lane = threadIdx.x & 63;
    if (wave >= nrows) return;
    const float* p = src + (size_t)wave * C_DIM + lane * 8;
    float4 a = *(const float4*)p;
    float4 b = *(const float4*)(p + 4);
    float s = a.x*a.x + a.y*a.y + a.z*a.z + a.w*a.w
            + b.x*b.x + b.y*b.y + b.z*b.z + b.w*b.w;
    #pragma unroll
    for (int off = 1; off < 64; off <<= 1) s += __shfl_xor(s, off);
    if (lane == 0) dst[wave] = s;
}

// -------- distance GEMM + fused per-column-block argmin --------
// dist(n,k) = ze2[n] - 2*dot(ze[n], cb[k]) + c2[k];  writes per-(row, colblock)
// partial (minval, global code idx) with first-index tie-breaking.
__global__ __launch_bounds__(256) void dist_argmin_kernel(
    const float* __restrict__ ze, const float* __restrict__ cb,
    const float* __restrict__ c2, const float* __restrict__ ze2,
    float* __restrict__ pmin, int* __restrict__ pidx)
{
    __shared__ float As[BM][BK + PAD];
    __shared__ float Bs[BN][BK + PAD];

    const int bm = blockIdx.x;           // row block (512)
    const int bn = blockIdx.y;           // code block (8)
    const int tid = threadIdx.x;
    const int tx = tid & 15;             // code-group: codes tx + 16*j
    const int ty = tid >> 4;             // row-group: rows ty*4 + i
    const int row0 = bm * BM;
    const int col0 = bn * BN;

    float acc[4][8];
    #pragma unroll
    for (int i = 0; i < 4; ++i)
        #pragma unroll
        for (int j = 0; j < 8; ++j) acc[i][j] = 0.f;

    for (int kk = 0; kk < C_DIM; kk += BK) {
        __syncthreads();
        // A tile: 64 rows x 32 cols = 512 float4, 2 per thread
        #pragma unroll
        for (int u = 0; u < 2; ++u) {
            int id = tid + u * 256;
            int m = id >> 3, f = id & 7;
            float4 v = *(const float4*)(ze + (size_t)(row0 + m) * C_DIM + kk + f * 4);
            *(float4*)(&As[m][f * 4]) = v;
        }
        // B tile: 128 codes x 32 cols = 1024 float4, 4 per thread
        #pragma unroll
        for (int u = 0; u < 4; ++u) {
            int id = tid + u * 256;
            int n = id >> 3, f = id & 7;
            float4 v = *(const float4*)(cb + (size_t)(col0 + n) * C_DIM + kk + f * 4);
            *(float4*)(&Bs[n][f * 4]) = v;
        }
        __syncthreads();
        #pragma unroll
        for (int b4 = 0; b4 < 8; ++b4) {
            float4 a[4], b[8];
            #pragma unroll
            for (int i = 0; i < 4; ++i)
                a[i] = *(const float4*)(&As[ty * 4 + i][b4 * 4]);
            #pragma unroll
            for (int j = 0; j < 8; ++j)
                b[j] = *(const float4*)(&Bs[tx + 16 * j][b4 * 4]);
            #pragma unroll
            for (int i = 0; i < 4; ++i)
                #pragma unroll
                for (int j = 0; j < 8; ++j) {
                    acc[i][j] += a[i].x * b[j].x;
                    acc[i][j] += a[i].y * b[j].y;
                    acc[i][j] += a[i].z * b[j].z;
                    acc[i][j] += a[i].w * b[j].w;
                }
        }
    }

    // epilogue: per-row argmin over this block's 128 codes
    #pragma unroll
    for (int i = 0; i < 4; ++i) {
        int r = row0 + ty * 4 + i;
        float z2 = ze2[r];
        float bv = 3.4e38f;
        int   bi = 0x7fffffff;
        #pragma unroll
        for (int j = 0; j < 8; ++j) {
            int code = col0 + tx + 16 * j;
            float d = z2 - 2.f * acc[i][j] + c2[code];
            if (d < bv || (d == bv && code < bi)) { bv = d; bi = code; }
        }
        // reduce across the 16 lanes sharing this row (same ty)
        #pragma unroll
        for (int off = 1; off < 16; off <<= 1) {
            float ov = __shfl_xor(bv, off);
            int   oi = __shfl_xor(bi, off);
            if (ov < bv || (ov == bv && oi < bi)) { bv = ov; bi = oi; }
        }
        if (tx == 0) {
            pmin[(size_t)r * NCOLB + bn] = bv;
            pidx[(size_t)r * NCOLB + bn] = bi;
        }
    }
}

// -------- per-stage update: pick winner, lookup, residual, loss partial ------
__global__ __launch_bounds__(256) void update_kernel(
    const float* __restrict__ ze_cur, const float* __restrict__ cb,
    const float* __restrict__ pmin, const int* __restrict__ pidx,
    float* __restrict__ quant, float* __restrict__ ze_next,
    float* __restrict__ ze2)
{
    int wave = (blockIdx.x * blockDim.x + threadIdx.x) >> 6;
    int lane = threadIdx.x & 63;
    if (wave >= N_ROWS) return;
    const int r = wave;

    float bv = pmin[(size_t)r * NCOLB + (lane & 7)];
    int   bi = pidx[(size_t)r * NCOLB + (lane & 7)];
    #pragma unroll
    for (int off = 1; off < 8; off <<= 1) {
        float ov = __shfl_xor(bv, off);
        int   oi = __shfl_xor(bi, off);
        if (ov < bv || (ov == bv && oi < bi)) { bv = ov; bi = oi; }
    }

    const float* zq = cb + (size_t)bi * C_DIM + lane * 8;
    size_t base = (size_t)r * C_DIM + lane * 8;

    float4 z0 = *(const float4*)(ze_cur + base);
    float4 z1 = *(const float4*)(ze_cur + base + 4);
    float4 q0 = *(const float4*)(zq);
    float4 q1 = *(const float4*)(zq + 4);

    float4 t0 = *(const float4*)(quant + base);
    float4 t1 = *(const float4*)(quant + base + 4);
    t0.x += q0.x; t0.y += q0.y; t0.z += q0.z; t0.w += q0.w;
    t1.x += q1.x; t1.y += q1.y; t1.z += q1.z; t1.w += q1.w;
    *(float4*)(quant + base)     = t0;
    *(float4*)(quant + base + 4) = t1;

    float4 n0, n1;
    n0.x = z0.x - q0.x; n0.y = z0.y - q0.y; n0.z = z0.z - q0.z; n0.w = z0.w - q0.w;
    n1.x = z1.x - q1.x; n1.y = z1.y - q1.y; n1.z = z1.z - q1.z; n1.w = z1.w - q1.w;
    *(float4*)(ze_next + base)     = n0;
    *(float4*)(ze_next + base + 4) = n1;

    float s = n0.x*n0.x + n0.y*n0.y + n0.z*n0.z + n0.w*n0.w
            + n1.x*n1.x + n1.y*n1.y + n1.z*n1.z + n1.w*n1.w;
    #pragma unroll
    for (int off = 1; off < 64; off <<= 1) s += __shfl_xor(s, off);
    if (lane == 0) ze2[r] = s;   // feeds next stage's dist AND this stage's loss
}

// -------- deterministic reduce of per-row resid^2 into one stage slot -------
__global__ __launch_bounds__(1024) void reduce_ze2_kernel(
    const float* __restrict__ ze2, float* __restrict__ out_slot)
{
    __shared__ float sm[1024];
    float s = 0.f;
    for (int i = threadIdx.x; i < N_ROWS; i += 1024) s += ze2[i];
    sm[threadIdx.x] = s;
    __syncthreads();
    for (int w = 512; w > 0; w >>= 1) {
        if ((int)threadIdx.x < w) sm[threadIdx.x] += sm[threadIdx.x + w];
        __syncthreads();
    }
    if (threadIdx.x == 0) *out_slot = sm[0];
}

__global__ void finalize_kernel(const float* __restrict__ lossbuf,
                                float* __restrict__ out)
{
    if (threadIdx.x == 0) {
        float s = 0.f;
        #pragma unroll
        for (int i = 0; i < Q_STAGES; ++i) s += lossbuf[i];
        out[0] = 2.75f * s / (float)((size_t)N_ROWS * C_DIM);
    }
}

extern "C" void kernel_launch(void* const* d_in, const int* in_sizes, int n_in,
                              void* d_out, int out_size, void* d_ws, size_t ws_size,
                              hipStream_t stream)
{
    const float* x   = (const float*)d_in[0];   // [N, C]
    const float* cbs = (const float*)d_in[1];   // [Q, K, C]
    float* out = (float*)d_out;                 // [N*C] quant_sum, then 1 loss
    char* ws = (char*)d_ws;

    float* ze    = (float*)(ws + ZE_OFF);
    float* ze2   = (float*)(ws + ZE2_OFF);
    float* c2    = (float*)(ws + C2_OFF);
    float* pmin  = (float*)(ws + PMIN_OFF);
    int*   pidx  = (int*)  (ws + PIDX_OFF);
    float* lossb = (float*)(ws + LOSS_OFF);

    // quant_sum accumulates in d_out; harness poisons it -> zero it ourselves.
    hipMemsetAsync(d_out, 0, (size_t)N_ROWS * C_DIM * sizeof(float), stream);

    // ze2 of x (stage 0) and codebook norms
    rowsq_kernel<<<(N_ROWS * 64) / 256, 256, 0, stream>>>(x, ze2, N_ROWS);
    rowsq_kernel<<<(Q_STAGES * K_CODES * 64) / 256, 256, 0, stream>>>(
        cbs, c2, Q_STAGES * K_CODES);

    for (int s = 0; s < Q_STAGES; ++s) {
        const float* zec = (s == 0) ? x : ze;
        const float* cb  = cbs + (size_t)s * K_CODES * C_DIM;
        dist_argmin_kernel<<<dim3(N_ROWS / BM, K_CODES / BN), 256, 0, stream>>>(
            zec, cb, c2 + (size_t)s * K_CODES, ze2, pmin, pidx);
        update_kernel<<<(N_ROWS * 64) / 256, 256, 0, stream>>>(
            zec, cb, pmin, pidx, out, ze, ze2);
        reduce_ze2_kernel<<<1, 1024, 0, stream>>>(ze2, lossb + s);
    }
    finalize_kernel<<<1, 64, 0, stream>>>(lossb, out + (size_t)N_ROWS * C_DIM);
}

// Round 2
// 1352.752 us; speedup vs baseline: 3.7369x; 3.7369x over previous
//
#include <hip/hip_runtime.h>

#define N_ROWS 32768
#define C_DIM  512
#define K_CODES 1024
#define Q_STAGES 8

typedef __attribute__((ext_vector_type(8))) short bf16x8;      // 8 bf16 (4 VGPR)
typedef __attribute__((ext_vector_type(4))) float f32x4;       // MFMA acc
typedef __attribute__((ext_vector_type(4))) unsigned short u16x4;
typedef __attribute__((ext_vector_type(8))) unsigned short u16x8;

// workspace layout (bytes) — total 69,312,544 <= proven 69.37MB budget
#define ZEH_OFF 0ull          // [N][C] ushort (bf16 hi)  33,554,432
#define ZEL_OFF 33554432ull   // [N][C] ushort (bf16 lo)  33,554,432
#define CBH_OFF 67108864ull   // [K][C] ushort, current stage  1,048,576
#define CBL_OFF 68157440ull   // [K][C] ushort               1,048,576
#define C2_OFF  69206016ull   // [Q][K] float                    32,768
#define IDX_OFF 69238784ull   // [N] ushort                      65,536
#define RPT_OFF 69304320ull   // [2048] float                     8,192
#define LSB_OFF 69312512ull   // [8] float                           32

#define GLD(gp, lp) __builtin_amdgcn_global_load_lds( \
    (const __attribute__((address_space(1))) void*)(gp), \
    (__attribute__((address_space(3))) void*)(lp), 16, 0, 0)

__device__ __forceinline__ float bf_hi_f(float f) {
    return __uint_as_float(__float_as_uint(f) & 0xFFFF0000u);
}
__device__ __forceinline__ unsigned short bf_hi_u(float f) {
    return (unsigned short)(__float_as_uint(f) >> 16);
}
__device__ __forceinline__ float u2f(unsigned short u) {
    return __uint_as_float(((unsigned int)u) << 16);
}

// ---- split fp32 -> (hi, lo) bf16 pair, 4 elems/thread ----
__global__ __launch_bounds__(256) void split_kernel(
    const float* __restrict__ src, unsigned short* __restrict__ h,
    unsigned short* __restrict__ l, int n4)
{
    int i = blockIdx.x * 256 + threadIdx.x;
    if (i >= n4) return;
    float4 v = *(const float4*)(src + (size_t)i * 4);
    u16x4 hv, lv;
    float f, hf;
    f = v.x; hv[0] = bf_hi_u(f); hf = bf_hi_f(f); lv[0] = bf_hi_u(f - hf);
    f = v.y; hv[1] = bf_hi_u(f); hf = bf_hi_f(f); lv[1] = bf_hi_u(f - hf);
    f = v.z; hv[2] = bf_hi_u(f); hf = bf_hi_f(f); lv[2] = bf_hi_u(f - hf);
    f = v.w; hv[3] = bf_hi_u(f); hf = bf_hi_f(f); lv[3] = bf_hi_u(f - hf);
    *(u16x4*)(h + (size_t)i * 4) = hv;
    *(u16x4*)(l + (size_t)i * 4) = lv;
}

// ---- row sum-of-squares (codebook norms), one wave per 512-float row ----
__global__ __launch_bounds__(256) void rowsq_kernel(
    const float* __restrict__ src, float* __restrict__ dst, int nrows)
{
    int wave = (blockIdx.x * blockDim.x + threadIdx.x) >> 6;
    int lane = threadIdx.x & 63;
    if (wave >= nrows) return;
    const float* p = src + (size_t)wave * C_DIM + lane * 8;
    float4 a = *(const float4*)p;
    float4 b = *(const float4*)(p + 4);
    float s = a.x*a.x + a.y*a.y + a.z*a.z + a.w*a.w
            + b.x*b.x + b.y*b.y + b.z*b.z + b.w*b.w;
    #pragma unroll
    for (int off = 1; off < 64; off <<= 1) s += __shfl_xor(s, off);
    if (lane == 0) dst[wave] = s;
}

// ---- MFMA distance + full argmin: block = 64 rows x ALL 1024 codes ----
// 8 waves (2M x 4N), wave tile 32x64, 16x16x32 bf16 MFMA, 3 passes (hh,hl,lh).
#define DBM 64
#define DBNC 256   // codes per chunk, 4 chunks
#define DBK 32

__global__ __launch_bounds__(512, 4) void dist_kernel(
    const unsigned short* __restrict__ zeh, const unsigned short* __restrict__ zel,
    const unsigned short* __restrict__ cbh, const unsigned short* __restrict__ cbl,
    const float* __restrict__ c2s, unsigned short* __restrict__ idx_out)
{
    __shared__ unsigned short sAh[DBM * DBK], sAl[DBM * DBK];
    __shared__ unsigned short sBh[DBNC * DBK], sBl[DBNC * DBK];
    __shared__ float s_v[DBM][4];
    __shared__ int   s_i[DBM][4];

    const int tid  = threadIdx.x;
    const int lane = tid & 63;
    const int w    = tid >> 6;     // wave 0..7
    const int wr   = w >> 2;       // 0..1 (M)
    const int wc   = w & 3;        // 0..3 (N)
    const int lr   = lane & 15;    // frag row/col
    const int kg   = lane >> 4;    // frag k-group
    const int row0 = blockIdx.x * DBM;

    // staging lane mapping: 16 rows x 64B per wave-issue
    const int srow = lane >> 2;
    const int scol = (lane & 3) * 8;

    float rbv[2][4];
    int   rbi[2][4];
    #pragma unroll
    for (int i = 0; i < 2; ++i)
        #pragma unroll
        for (int r = 0; r < 4; ++r) { rbv[i][r] = 3.4e38f; rbi[i][r] = 0x7fffffff; }

    for (int ncc = 0; ncc < 4; ++ncc) {
        const int col0 = ncc * DBNC;
        f32x4 acc[2][4];
        #pragma unroll
        for (int i = 0; i < 2; ++i)
            #pragma unroll
            for (int j = 0; j < 4; ++j) acc[i][j] = (f32x4)0.f;

        for (int kk = 0; kk < C_DIM; kk += DBK) {
            __syncthreads();
            // A: waves 0-3 stage hi, 4-7 stage lo (16 rows each)
            if (w < 4) {
                GLD(zeh + (size_t)(row0 + w * 16 + srow) * C_DIM + kk + scol,
                    &sAh[(w * 16) * DBK]);
            } else {
                GLD(zel + (size_t)(row0 + (w - 4) * 16 + srow) * C_DIM + kk + scol,
                    &sAl[((w - 4) * 16) * DBK]);
            }
            // B: each wave stages 32 rows of hi and 32 of lo
            #pragma unroll
            for (int u = 0; u < 2; ++u) {
                GLD(cbh + (size_t)(col0 + w * 32 + u * 16 + srow) * C_DIM + kk + scol,
                    &sBh[(w * 32 + u * 16) * DBK]);
                GLD(cbl + (size_t)(col0 + w * 32 + u * 16 + srow) * C_DIM + kk + scol,
                    &sBl[(w * 32 + u * 16) * DBK]);
            }
            __syncthreads();

            bf16x8 ah[2], al[2], bh[4], bl[4];
            #pragma unroll
            for (int mi = 0; mi < 2; ++mi) {
                int rowoff = (wr * 32 + mi * 16 + lr) * DBK + kg * 8;
                ah[mi] = *(const bf16x8*)&sAh[rowoff];
                al[mi] = *(const bf16x8*)&sAl[rowoff];
            }
            #pragma unroll
            for (int ni = 0; ni < 4; ++ni) {
                int rowoff = (wc * 64 + ni * 16 + lr) * DBK + kg * 8;
                bh[ni] = *(const bf16x8*)&sBh[rowoff];
                bl[ni] = *(const bf16x8*)&sBl[rowoff];
            }
            #pragma unroll
            for (int mi = 0; mi < 2; ++mi)
                #pragma unroll
                for (int ni = 0; ni < 4; ++ni) {
                    acc[mi][ni] = __builtin_amdgcn_mfma_f32_16x16x32_bf16(
                        ah[mi], bh[ni], acc[mi][ni], 0, 0, 0);
                    acc[mi][ni] = __builtin_amdgcn_mfma_f32_16x16x32_bf16(
                        ah[mi], bl[ni], acc[mi][ni], 0, 0, 0);
                    acc[mi][ni] = __builtin_amdgcn_mfma_f32_16x16x32_bf16(
                        al[mi], bh[ni], acc[mi][ni], 0, 0, 0);
                }
        }

        // per-chunk epilogue: d = c2 - 2*dot ; codes ascend (strict < keeps first)
        #pragma unroll
        for (int ni = 0; ni < 4; ++ni) {
            int code = col0 + wc * 64 + ni * 16 + lr;
            float c2v = c2s[code];
            #pragma unroll
            for (int mi = 0; mi < 2; ++mi)
                #pragma unroll
                for (int r = 0; r < 4; ++r) {
                    float d = fmaf(-2.f, acc[mi][ni][r], c2v);
                    if (d < rbv[mi][r]) { rbv[mi][r] = d; rbi[mi][r] = code; }
                }
        }
    }

    // reduce across the 16 lanes (lr) sharing each row
    #pragma unroll
    for (int off = 1; off < 16; off <<= 1) {
        #pragma unroll
        for (int mi = 0; mi < 2; ++mi)
            #pragma unroll
            for (int r = 0; r < 4; ++r) {
                float ov = __shfl_xor(rbv[mi][r], off);
                int   oi = __shfl_xor(rbi[mi][r], off);
                if (ov < rbv[mi][r] || (ov == rbv[mi][r] && oi < rbi[mi][r])) {
                    rbv[mi][r] = ov; rbi[mi][r] = oi;
                }
            }
    }
    if (lr == 0) {
        #pragma unroll
        for (int mi = 0; mi < 2; ++mi)
            #pragma unroll
            for (int r = 0; r < 4; ++r) {
                int lrow = wr * 32 + mi * 16 + kg * 4 + r;
                s_v[lrow][wc] = rbv[mi][r];
                s_i[lrow][wc] = rbi[mi][r];
            }
    }
    __syncthreads();
    if (tid < DBM) {
        float bv = s_v[tid][0]; int bi = s_i[tid][0];
        #pragma unroll
        for (int c = 1; c < 4; ++c) {
            float v = s_v[tid][c]; int i = s_i[tid][c];
            if (v < bv || (v == bv && i < bi)) { bv = v; bi = i; }
        }
        idx_out[row0 + tid] = (unsigned short)bi;
    }
}

// ---- per-stage update: lookup, quant accum, residual (fp32->hi/lo), loss ----
__global__ __launch_bounds__(1024) void update_kernel(
    const int s, const float* __restrict__ x, const float* __restrict__ cb,
    const unsigned short* __restrict__ idx_sel, float* __restrict__ out,
    unsigned short* __restrict__ zeh, unsigned short* __restrict__ zel,
    float* __restrict__ rpart)
{
    __shared__ float swsum[16];
    const int wid = threadIdx.x >> 6, lane = threadIdx.x & 63;
    const int r = blockIdx.x * 16 + wid;
    const int bi = idx_sel[r];
    const size_t base = (size_t)r * C_DIM + lane * 8;
    const float* q = cb + (size_t)bi * C_DIM + lane * 8;

    float4 q0 = *(const float4*)q;
    float4 q1 = *(const float4*)(q + 4);
    float qq[8] = {q0.x, q0.y, q0.z, q0.w, q1.x, q1.y, q1.z, q1.w};

    float v[8];
    if (s == 0) {
        float4 z0 = *(const float4*)(x + base);
        float4 z1 = *(const float4*)(x + base + 4);
        v[0]=z0.x; v[1]=z0.y; v[2]=z0.z; v[3]=z0.w;
        v[4]=z1.x; v[5]=z1.y; v[6]=z1.z; v[7]=z1.w;
    } else {
        u16x8 h = *(const u16x8*)(zeh + base);
        u16x8 l = *(const u16x8*)(zel + base);
        #pragma unroll
        for (int j = 0; j < 8; ++j) v[j] = u2f(h[j]) + u2f(l[j]);
    }

    // quant_sum += z_q
    float4 o0 = *(const float4*)(out + base);
    float4 o1 = *(const float4*)(out + base + 4);
    o0.x += q0.x; o0.y += q0.y; o0.z += q0.z; o0.w += q0.w;
    o1.x += q1.x; o1.y += q1.y; o1.z += q1.z; o1.w += q1.w;
    *(float4*)(out + base)     = o0;
    *(float4*)(out + base + 4) = o1;

    float rr[8];
    #pragma unroll
    for (int j = 0; j < 8; ++j) rr[j] = v[j] - qq[j];

    if (s < Q_STAGES - 1) {
        u16x8 hh, ll;
        #pragma unroll
        for (int j = 0; j < 8; ++j) {
            hh[j] = bf_hi_u(rr[j]);
            float lo = rr[j] - bf_hi_f(rr[j]);
            ll[j] = bf_hi_u(lo);
        }
        *(u16x8*)(zeh + base) = hh;
        *(u16x8*)(zel + base) = ll;
    }

    float ssum = 0.f;
    #pragma unroll
    for (int j = 0; j < 8; ++j) ssum += rr[j] * rr[j];
    #pragma unroll
    for (int off = 1; off < 64; off <<= 1) ssum += __shfl_xor(ssum, off);
    if (lane == 0) swsum[wid] = ssum;
    __syncthreads();
    if (threadIdx.x == 0) {
        float t = 0.f;
        #pragma unroll
        for (int i = 0; i < 16; ++i) t += swsum[i];
        rpart[blockIdx.x] = t;
    }
}

__global__ __launch_bounds__(1024) void reduce2048_kernel(
    const float* __restrict__ rpart, float* __restrict__ slot)
{
    __shared__ float sm[1024];
    int t = threadIdx.x;
    sm[t] = rpart[t] + rpart[t + 1024];
    __syncthreads();
    for (int w2 = 512; w2 > 0; w2 >>= 1) {
        if (t < w2) sm[t] += sm[t + w2];
        __syncthreads();
    }
    if (t == 0) *slot = sm[0];
}

__global__ void finalize_kernel(const float* __restrict__ lossbuf,
                                float* __restrict__ out)
{
    if (threadIdx.x == 0) {
        float s = 0.f;
        #pragma unroll
        for (int i = 0; i < Q_STAGES; ++i) s += lossbuf[i];
        out[0] = 2.75f * s / (float)((size_t)N_ROWS * C_DIM);
    }
}

extern "C" void kernel_launch(void* const* d_in, const int* in_sizes, int n_in,
                              void* d_out, int out_size, void* d_ws, size_t ws_size,
                              hipStream_t stream)
{
    const float* x   = (const float*)d_in[0];   // [N, C]
    const float* cbs = (const float*)d_in[1];   // [Q, K, C]
    float* out = (float*)d_out;                 // [N*C] quant_sum, then 1 loss
    char* ws = (char*)d_ws;

    unsigned short* zeh = (unsigned short*)(ws + ZEH_OFF);
    unsigned short* zel = (unsigned short*)(ws + ZEL_OFF);
    unsigned short* cbh = (unsigned short*)(ws + CBH_OFF);
    unsigned short* cbl = (unsigned short*)(ws + CBL_OFF);
    float* c2    = (float*)(ws + C2_OFF);
    unsigned short* gidx = (unsigned short*)(ws + IDX_OFF);
    float* rpart = (float*)(ws + RPT_OFF);
    float* lossb = (float*)(ws + LSB_OFF);

    hipMemsetAsync(d_out, 0, (size_t)N_ROWS * C_DIM * sizeof(float), stream);

    // x -> hi/lo bf16; codebook norms (fp32 exact)
    split_kernel<<<(N_ROWS * C_DIM / 4 + 255) / 256, 256, 0, stream>>>(
        x, zeh, zel, N_ROWS * C_DIM / 4);
    rowsq_kernel<<<(Q_STAGES * K_CODES * 64) / 256, 256, 0, stream>>>(
        cbs, c2, Q_STAGES * K_CODES);

    for (int s = 0; s < Q_STAGES; ++s) {
        const float* cb = cbs + (size_t)s * K_CODES * C_DIM;
        split_kernel<<<(K_CODES * C_DIM / 4 + 255) / 256, 256, 0, stream>>>(
            cb, cbh, cbl, K_CODES * C_DIM / 4);
        dist_kernel<<<N_ROWS / DBM, 512, 0, stream>>>(
            zeh, zel, cbh, cbl, c2 + (size_t)s * K_CODES, gidx);
        update_kernel<<<N_ROWS / 16, 1024, 0, stream>>>(
            s, x, cb, gidx, out, zeh, zel, rpart);
        reduce2048_kernel<<<1, 1024, 0, stream>>>(rpart, lossb + s);
    }
    finalize_kernel<<<1, 64, 0, stream>>>(lossb, out + (size_t)N_ROWS * C_DIM);
}

// Round 3
// 1290.774 us; speedup vs baseline: 3.9163x; 1.0480x over previous
//
#include <hip/hip_runtime.h>

#define N_ROWS 32768
#define C_DIM  512
#define K_CODES 1024
#define Q_STAGES 8

typedef __attribute__((ext_vector_type(8))) short bf16x8;      // 8 bf16 (4 VGPR)
typedef __attribute__((ext_vector_type(4))) float f32x4;       // MFMA acc
typedef __attribute__((ext_vector_type(4))) unsigned short u16x4;
typedef __attribute__((ext_vector_type(8))) unsigned short u16x8;

// workspace layout (bytes) — total 69,312,544 <= proven 69.37MB budget
#define ZEH_OFF 0ull          // [N][C] ushort (bf16 hi)  33,554,432
#define ZEL_OFF 33554432ull   // [N][C] ushort (bf16 lo)  33,554,432
#define CBH_OFF 67108864ull   // [K][C] ushort, current stage  1,048,576
#define CBL_OFF 68157440ull   // [K][C] ushort               1,048,576
#define C2_OFF  69206016ull   // [Q][K] float                    32,768
#define IDX_OFF 69238784ull   // [N] ushort                      65,536
#define RPT_OFF 69304320ull   // [2048] float                     8,192
#define LSB_OFF 69312512ull   // [8] float                           32

#define GLD(gp, lp) __builtin_amdgcn_global_load_lds( \
    (const __attribute__((address_space(1))) void*)(gp), \
    (__attribute__((address_space(3))) void*)(lp), 16, 0, 0)

__device__ __forceinline__ float bf_hi_f(float f) {
    return __uint_as_float(__float_as_uint(f) & 0xFFFF0000u);
}
__device__ __forceinline__ unsigned short bf_hi_u(float f) {
    return (unsigned short)(__float_as_uint(f) >> 16);
}
__device__ __forceinline__ float u2f(unsigned short u) {
    return __uint_as_float(((unsigned int)u) << 16);
}

// ---- split fp32 -> (hi, lo) bf16 pair, 4 elems/thread ----
__global__ __launch_bounds__(256) void split_kernel(
    const float* __restrict__ src, unsigned short* __restrict__ h,
    unsigned short* __restrict__ l, int n4)
{
    int i = blockIdx.x * 256 + threadIdx.x;
    if (i >= n4) return;
    float4 v = *(const float4*)(src + (size_t)i * 4);
    u16x4 hv, lv;
    float f, hf;
    f = v.x; hv[0] = bf_hi_u(f); hf = bf_hi_f(f); lv[0] = bf_hi_u(f - hf);
    f = v.y; hv[1] = bf_hi_u(f); hf = bf_hi_f(f); lv[1] = bf_hi_u(f - hf);
    f = v.z; hv[2] = bf_hi_u(f); hf = bf_hi_f(f); lv[2] = bf_hi_u(f - hf);
    f = v.w; hv[3] = bf_hi_u(f); hf = bf_hi_f(f); lv[3] = bf_hi_u(f - hf);
    *(u16x4*)(h + (size_t)i * 4) = hv;
    *(u16x4*)(l + (size_t)i * 4) = lv;
}

// ---- row sum-of-squares (codebook norms), one wave per 512-float row ----
__global__ __launch_bounds__(256) void rowsq_kernel(
    const float* __restrict__ src, float* __restrict__ dst, int nrows)
{
    int wave = (blockIdx.x * blockDim.x + threadIdx.x) >> 6;
    int lane = threadIdx.x & 63;
    if (wave >= nrows) return;
    const float* p = src + (size_t)wave * C_DIM + lane * 8;
    float4 a = *(const float4*)p;
    float4 b = *(const float4*)(p + 4);
    float s = a.x*a.x + a.y*a.y + a.z*a.z + a.w*a.w
            + b.x*b.x + b.y*b.y + b.z*b.z + b.w*b.w;
    #pragma unroll
    for (int off = 1; off < 64; off <<= 1) s += __shfl_xor(s, off);
    if (lane == 0) dst[wave] = s;
}

// ---- MFMA distance + full argmin: block = 64 rows x ALL 1024 codes ----
// 8 waves (2M x 4N), wave tile 32x64, 16x16x32 bf16 MFMA, 3 passes (hh,hl,lh).
// T3-min 2-phase double-buffer (1 barrier/K-step) + T2 16B-slot XOR swizzle.
#define DBM 64
#define DBNC 256   // codes per chunk, 4 chunks
#define DBK 32
#define NSTEPS 64  // 4 chunks * 16 K-steps

__global__ __launch_bounds__(512, 4) void dist_kernel(
    const unsigned short* __restrict__ zeh, const unsigned short* __restrict__ zel,
    const unsigned short* __restrict__ cbh, const unsigned short* __restrict__ cbl,
    const float* __restrict__ c2s, unsigned short* __restrict__ idx_out)
{
    // double-buffered staging: sA[buf][hi/lo][64*32], sB[buf][hi/lo][256*32]
    __shared__ unsigned short sA[2][2][DBM * DBK];    // 16 KiB
    __shared__ unsigned short sB[2][2][DBNC * DBK];   // 64 KiB  (total 80 KiB)

    const int tid  = threadIdx.x;
    const int lane = tid & 63;
    const int w    = tid >> 6;     // wave 0..7
    const int wr   = w >> 2;       // 0..1 (M)
    const int wc   = w & 3;        // 0..3 (N)
    const int lr   = lane & 15;    // frag row/col
    const int kg   = lane >> 4;    // frag k-group
    const int row0 = blockIdx.x * DBM;

    // staging lane mapping: 16 rows x 64B per wave-issue, swizzled 16B slot
    const int srow = lane >> 2;
    const int scol = (((lane & 3) ^ ((srow >> 1) & 3))) * 8;  // elements

    // read-side swizzled k-slot (row>>1)&3 == (lr>>1)&3 for all our rows
    const int aslot = (kg ^ ((lr >> 1) & 3)) * 8;

    float rbv[2][4];
    int   rbi[2][4];
    #pragma unroll
    for (int i = 0; i < 2; ++i)
        #pragma unroll
        for (int r = 0; r < 4; ++r) { rbv[i][r] = 3.4e38f; rbi[i][r] = 0x7fffffff; }

    f32x4 acc[2][4];
    #pragma unroll
    for (int i = 0; i < 2; ++i)
        #pragma unroll
        for (int j = 0; j < 4; ++j) acc[i][j] = (f32x4)0.f;

    auto stage = [&](int t, int b) {
        const int col0 = (t >> 4) * DBNC;
        const int kk = (t & 15) * DBK;
        // A: waves 0-3 stage hi, 4-7 stage lo (16 rows each)
        if (w < 4) {
            GLD(zeh + (size_t)(row0 + w * 16 + srow) * C_DIM + kk + scol,
                &sA[b][0][(w * 16) * DBK]);
        } else {
            GLD(zel + (size_t)(row0 + (w - 4) * 16 + srow) * C_DIM + kk + scol,
                &sA[b][1][((w - 4) * 16) * DBK]);
        }
        // B: each wave stages 32 rows of hi and 32 of lo
        #pragma unroll
        for (int u = 0; u < 2; ++u) {
            const int rB = w * 32 + u * 16;
            GLD(cbh + (size_t)(col0 + rB + srow) * C_DIM + kk + scol,
                &sB[b][0][rB * DBK]);
            GLD(cbl + (size_t)(col0 + rB + srow) * C_DIM + kk + scol,
                &sB[b][1][rB * DBK]);
        }
    };

    stage(0, 0);
    __syncthreads();

    int buf = 0;
    for (int t = 0; t < NSTEPS; ++t) {
        if (t < NSTEPS - 1) stage(t + 1, buf ^ 1);   // loads fly under MFMA

        bf16x8 ah[2], al[2], bh[4], bl[4];
        #pragma unroll
        for (int mi = 0; mi < 2; ++mi) {
            const int rowoff = (wr * 32 + mi * 16 + lr) * DBK + aslot;
            ah[mi] = *(const bf16x8*)&sA[buf][0][rowoff];
            al[mi] = *(const bf16x8*)&sA[buf][1][rowoff];
        }
        #pragma unroll
        for (int ni = 0; ni < 4; ++ni) {
            const int rowoff = (wc * 64 + ni * 16 + lr) * DBK + aslot;
            bh[ni] = *(const bf16x8*)&sB[buf][0][rowoff];
            bl[ni] = *(const bf16x8*)&sB[buf][1][rowoff];
        }
        #pragma unroll
        for (int mi = 0; mi < 2; ++mi)
            #pragma unroll
            for (int ni = 0; ni < 4; ++ni) {
                acc[mi][ni] = __builtin_amdgcn_mfma_f32_16x16x32_bf16(
                    ah[mi], bh[ni], acc[mi][ni], 0, 0, 0);
                acc[mi][ni] = __builtin_amdgcn_mfma_f32_16x16x32_bf16(
                    ah[mi], bl[ni], acc[mi][ni], 0, 0, 0);
                acc[mi][ni] = __builtin_amdgcn_mfma_f32_16x16x32_bf16(
                    al[mi], bh[ni], acc[mi][ni], 0, 0, 0);
            }

        if ((t & 15) == 15) {
            // chunk epilogue: d = c2 - 2*dot; codes ascend -> strict < keeps first
            const int col0 = (t >> 4) * DBNC;
            #pragma unroll
            for (int ni = 0; ni < 4; ++ni) {
                const int code = col0 + wc * 64 + ni * 16 + lr;
                const float c2v = c2s[code];
                #pragma unroll
                for (int mi = 0; mi < 2; ++mi)
                    #pragma unroll
                    for (int r = 0; r < 4; ++r) {
                        float d = fmaf(-2.f, acc[mi][ni][r], c2v);
                        if (d < rbv[mi][r]) { rbv[mi][r] = d; rbi[mi][r] = code; }
                    }
            }
            #pragma unroll
            for (int i = 0; i < 2; ++i)
                #pragma unroll
                for (int j = 0; j < 4; ++j) acc[i][j] = (f32x4)0.f;
        }
        __syncthreads();
        buf ^= 1;
    }

    // reduce across the 16 lanes (lr) sharing each row
    #pragma unroll
    for (int off = 1; off < 16; off <<= 1) {
        #pragma unroll
        for (int mi = 0; mi < 2; ++mi)
            #pragma unroll
            for (int r = 0; r < 4; ++r) {
                float ov = __shfl_xor(rbv[mi][r], off);
                int   oi = __shfl_xor(rbi[mi][r], off);
                if (ov < rbv[mi][r] || (ov == rbv[mi][r] && oi < rbi[mi][r])) {
                    rbv[mi][r] = ov; rbi[mi][r] = oi;
                }
            }
    }

    // cross-wave argmin via smem overlaid on sB (all reads done: barrier above)
    float (*s_v)[4] = (float (*)[4])&sB[0][0][0];
    int   (*s_i)[4] = (int (*)[4])(&sB[0][0][0] + DBM * 4 * 2);
    if (lr == 0) {
        #pragma unroll
        for (int mi = 0; mi < 2; ++mi)
            #pragma unroll
            for (int r = 0; r < 4; ++r) {
                int lrow = wr * 32 + mi * 16 + kg * 4 + r;
                s_v[lrow][wc] = rbv[mi][r];
                s_i[lrow][wc] = rbi[mi][r];
            }
    }
    __syncthreads();
    if (tid < DBM) {
        float bv = s_v[tid][0]; int bi = s_i[tid][0];
        #pragma unroll
        for (int c = 1; c < 4; ++c) {
            float v = s_v[tid][c]; int i = s_i[tid][c];
            if (v < bv || (v == bv && i < bi)) { bv = v; bi = i; }
        }
        idx_out[row0 + tid] = (unsigned short)bi;
    }
}

// ---- per-stage update: lookup, quant accum, residual (fp32->hi/lo), loss ----
__global__ __launch_bounds__(1024) void update_kernel(
    const int s, const float* __restrict__ x, const float* __restrict__ cb,
    const unsigned short* __restrict__ idx_sel, float* __restrict__ out,
    unsigned short* __restrict__ zeh, unsigned short* __restrict__ zel,
    float* __restrict__ rpart)
{
    __shared__ float swsum[16];
    const int wid = threadIdx.x >> 6, lane = threadIdx.x & 63;
    const int r = blockIdx.x * 16 + wid;
    const int bi = idx_sel[r];
    const size_t base = (size_t)r * C_DIM + lane * 8;
    const float* q = cb + (size_t)bi * C_DIM + lane * 8;

    float4 q0 = *(const float4*)q;
    float4 q1 = *(const float4*)(q + 4);
    float qq[8] = {q0.x, q0.y, q0.z, q0.w, q1.x, q1.y, q1.z, q1.w};

    float v[8];
    if (s == 0) {
        float4 z0 = *(const float4*)(x + base);
        float4 z1 = *(const float4*)(x + base + 4);
        v[0]=z0.x; v[1]=z0.y; v[2]=z0.z; v[3]=z0.w;
        v[4]=z1.x; v[5]=z1.y; v[6]=z1.z; v[7]=z1.w;
    } else {
        u16x8 h = *(const u16x8*)(zeh + base);
        u16x8 l = *(const u16x8*)(zel + base);
        #pragma unroll
        for (int j = 0; j < 8; ++j) v[j] = u2f(h[j]) + u2f(l[j]);
    }

    // quant_sum += z_q
    float4 o0 = *(const float4*)(out + base);
    float4 o1 = *(const float4*)(out + base + 4);
    o0.x += q0.x; o0.y += q0.y; o0.z += q0.z; o0.w += q0.w;
    o1.x += q1.x; o1.y += q1.y; o1.z += q1.z; o1.w += q1.w;
    *(float4*)(out + base)     = o0;
    *(float4*)(out + base + 4) = o1;

    float rr[8];
    #pragma unroll
    for (int j = 0; j < 8; ++j) rr[j] = v[j] - qq[j];

    if (s < Q_STAGES - 1) {
        u16x8 hh, ll;
        #pragma unroll
        for (int j = 0; j < 8; ++j) {
            hh[j] = bf_hi_u(rr[j]);
            float lo = rr[j] - bf_hi_f(rr[j]);
            ll[j] = bf_hi_u(lo);
        }
        *(u16x8*)(zeh + base) = hh;
        *(u16x8*)(zel + base) = ll;
    }

    float ssum = 0.f;
    #pragma unroll
    for (int j = 0; j < 8; ++j) ssum += rr[j] * rr[j];
    #pragma unroll
    for (int off = 1; off < 64; off <<= 1) ssum += __shfl_xor(ssum, off);
    if (lane == 0) swsum[wid] = ssum;
    __syncthreads();
    if (threadIdx.x == 0) {
        float t = 0.f;
        #pragma unroll
        for (int i = 0; i < 16; ++i) t += swsum[i];
        rpart[blockIdx.x] = t;
    }
}

__global__ __launch_bounds__(1024) void reduce2048_kernel(
    const float* __restrict__ rpart, float* __restrict__ slot)
{
    __shared__ float sm[1024];
    int t = threadIdx.x;
    sm[t] = rpart[t] + rpart[t + 1024];
    __syncthreads();
    for (int w2 = 512; w2 > 0; w2 >>= 1) {
        if (t < w2) sm[t] += sm[t + w2];
        __syncthreads();
    }
    if (t == 0) *slot = sm[0];
}

__global__ void finalize_kernel(const float* __restrict__ lossbuf,
                                float* __restrict__ out)
{
    if (threadIdx.x == 0) {
        float s = 0.f;
        #pragma unroll
        for (int i = 0; i < Q_STAGES; ++i) s += lossbuf[i];
        out[0] = 2.75f * s / (float)((size_t)N_ROWS * C_DIM);
    }
}

extern "C" void kernel_launch(void* const* d_in, const int* in_sizes, int n_in,
                              void* d_out, int out_size, void* d_ws, size_t ws_size,
                              hipStream_t stream)
{
    const float* x   = (const float*)d_in[0];   // [N, C]
    const float* cbs = (const float*)d_in[1];   // [Q, K, C]
    float* out = (float*)d_out;                 // [N*C] quant_sum, then 1 loss
    char* ws = (char*)d_ws;

    unsigned short* zeh = (unsigned short*)(ws + ZEH_OFF);
    unsigned short* zel = (unsigned short*)(ws + ZEL_OFF);
    unsigned short* cbh = (unsigned short*)(ws + CBH_OFF);
    unsigned short* cbl = (unsigned short*)(ws + CBL_OFF);
    float* c2    = (float*)(ws + C2_OFF);
    unsigned short* gidx = (unsigned short*)(ws + IDX_OFF);
    float* rpart = (float*)(ws + RPT_OFF);
    float* lossb = (float*)(ws + LSB_OFF);

    hipMemsetAsync(d_out, 0, (size_t)N_ROWS * C_DIM * sizeof(float), stream);

    // x -> hi/lo bf16; codebook norms (fp32 exact)
    split_kernel<<<(N_ROWS * C_DIM / 4 + 255) / 256, 256, 0, stream>>>(
        x, zeh, zel, N_ROWS * C_DIM / 4);
    rowsq_kernel<<<(Q_STAGES * K_CODES * 64) / 256, 256, 0, stream>>>(
        cbs, c2, Q_STAGES * K_CODES);

    for (int s = 0; s < Q_STAGES; ++s) {
        const float* cb = cbs + (size_t)s * K_CODES * C_DIM;
        split_kernel<<<(K_CODES * C_DIM / 4 + 255) / 256, 256, 0, stream>>>(
            cb, cbh, cbl, K_CODES * C_DIM / 4);
        dist_kernel<<<N_ROWS / DBM, 512, 0, stream>>>(
            zeh, zel, cbh, cbl, c2 + (size_t)s * K_CODES, gidx);
        update_kernel<<<N_ROWS / 16, 1024, 0, stream>>>(
            s, x, cb, gidx, out, zeh, zel, rpart);
        reduce2048_kernel<<<1, 1024, 0, stream>>>(rpart, lossb + s);
    }
    finalize_kernel<<<1, 64, 0, stream>>>(lossb, out + (size_t)N_ROWS * C_DIM);
}

// Round 4
// 1012.145 us; speedup vs baseline: 4.9945x; 1.2753x over previous
//
#include <hip/hip_runtime.h>

#define N_ROWS 32768
#define C_DIM  512
#define K_CODES 1024
#define Q_STAGES 8

typedef __attribute__((ext_vector_type(8))) short bf16x8;      // 8 bf16 (4 VGPR)
typedef __attribute__((ext_vector_type(4))) float f32x4;       // MFMA acc
typedef __attribute__((ext_vector_type(4))) unsigned short u16x4;
typedef __attribute__((ext_vector_type(8))) unsigned short u16x8;

// workspace layout (bytes) — total <= proven 69.37MB budget
#define ZEH_OFF 0ull          // [N][C] ushort (bf16 hi)  33,554,432
#define ZEL_OFF 33554432ull   // [N][C] ushort (bf16 lo)  33,554,432
#define CBH_OFF 67108864ull   // [K][C] ushort, current stage  1,048,576
#define CBL_OFF 68157440ull   // [K][C] ushort               1,048,576
#define C2_OFF  69206016ull   // [Q][K] float                    32,768
#define IDX_OFF 69238784ull   // [N] ushort                      65,536
#define RPT_OFF 69304320ull   // [2048] float                     8,192
#define LSB_OFF 69312512ull   // [8] float                           32

#define GLD(gp, lp) __builtin_amdgcn_global_load_lds( \
    (const __attribute__((address_space(1))) void*)(gp), \
    (__attribute__((address_space(3))) void*)(lp), 16, 0, 0)

__device__ __forceinline__ float bf_hi_f(float f) {
    return __uint_as_float(__float_as_uint(f) & 0xFFFF0000u);
}
__device__ __forceinline__ unsigned short bf_hi_u(float f) {
    return (unsigned short)(__float_as_uint(f) >> 16);
}
__device__ __forceinline__ float u2f(unsigned short u) {
    return __uint_as_float(((unsigned int)u) << 16);
}

// ---- split fp32 -> (hi, lo) bf16 pair, 4 elems/thread ----
__global__ __launch_bounds__(256) void split_kernel(
    const float* __restrict__ src, unsigned short* __restrict__ h,
    unsigned short* __restrict__ l, int n4)
{
    int i = blockIdx.x * 256 + threadIdx.x;
    if (i >= n4) return;
    float4 v = *(const float4*)(src + (size_t)i * 4);
    u16x4 hv, lv;
    float f, hf;
    f = v.x; hv[0] = bf_hi_u(f); hf = bf_hi_f(f); lv[0] = bf_hi_u(f - hf);
    f = v.y; hv[1] = bf_hi_u(f); hf = bf_hi_f(f); lv[1] = bf_hi_u(f - hf);
    f = v.z; hv[2] = bf_hi_u(f); hf = bf_hi_f(f); lv[2] = bf_hi_u(f - hf);
    f = v.w; hv[3] = bf_hi_u(f); hf = bf_hi_f(f); lv[3] = bf_hi_u(f - hf);
    *(u16x4*)(h + (size_t)i * 4) = hv;
    *(u16x4*)(l + (size_t)i * 4) = lv;
}

// ---- row sum-of-squares (codebook norms), one wave per 512-float row ----
__global__ __launch_bounds__(256) void rowsq_kernel(
    const float* __restrict__ src, float* __restrict__ dst, int nrows)
{
    int wave = (blockIdx.x * blockDim.x + threadIdx.x) >> 6;
    int lane = threadIdx.x & 63;
    if (wave >= nrows) return;
    const float* p = src + (size_t)wave * C_DIM + lane * 8;
    float4 a = *(const float4*)p;
    float4 b = *(const float4*)(p + 4);
    float s = a.x*a.x + a.y*a.y + a.z*a.z + a.w*a.w
            + b.x*b.x + b.y*b.y + b.z*b.z + b.w*b.w;
    #pragma unroll
    for (int off = 1; off < 64; off <<= 1) s += __shfl_xor(s, off);
    if (lane == 0) dst[wave] = s;
}

// ---- MFMA distance + full argmin ----
// Block = 128 rows x ALL 1024 codes (4 chunks of 256). 8 waves (2M x 4N),
// wave tile 64x64, 16x16x32 bf16 MFMA, 3 passes (hh,hl,lh).
// T3+T4: triple-buffer, depth-2 prefetch, counted vmcnt(6), 1 barrier/iter.
#define DBM2 128
#define DBNC 256
#define DBK 32
#define NSTEPS 64  // 4 chunks * 16 K-steps

__global__ __launch_bounds__(512, 2) void dist_kernel(
    const unsigned short* __restrict__ zeh, const unsigned short* __restrict__ zel,
    const unsigned short* __restrict__ cbh, const unsigned short* __restrict__ cbl,
    const float* __restrict__ c2s, unsigned short* __restrict__ idx_out)
{
    __shared__ unsigned short sA[3][2][DBM2 * DBK];   // 48 KiB
    __shared__ unsigned short sB[3][2][DBNC * DBK];   // 96 KiB
    __shared__ float c2_lds[K_CODES];                 // 4 KiB  (total 148 KiB)

    const int tid  = threadIdx.x;
    const int lane = tid & 63;
    const int w    = tid >> 6;     // wave 0..7
    const int wr   = w >> 2;       // 0..1 (M)
    const int wc   = w & 3;        // 0..3 (N)
    const int lr   = lane & 15;    // frag row/col
    const int kg   = lane >> 4;    // frag k-group
    const int row0 = blockIdx.x * DBM2;

    // c2 -> LDS (visible before first epilogue at t=15)
    for (int i = tid; i < K_CODES; i += 512) c2_lds[i] = c2s[i];

    // staging lane mapping: 16 rows x 64B per GLD issue, swizzled 16B slot
    const int srow = lane >> 2;
    const int scol = (((lane & 3) ^ ((srow >> 1) & 3))) * 8;  // elements
    const int aslot = (kg ^ ((lr >> 1) & 3)) * 8;             // read-side

    float rbv[4][4];
    int   rbi[4][4];
    #pragma unroll
    for (int i = 0; i < 4; ++i)
        #pragma unroll
        for (int r = 0; r < 4; ++r) { rbv[i][r] = 3.4e38f; rbi[i][r] = 0x7fffffff; }

    f32x4 acc[4][4];
    #pragma unroll
    for (int i = 0; i < 4; ++i)
        #pragma unroll
        for (int j = 0; j < 4; ++j) acc[i][j] = (f32x4)0.f;

    // each wave issues EXACTLY 6 GLDs per stage (vmcnt counting relies on it)
    auto stage = [&](int t, int b) {
        const int col0 = (t >> 4) * DBNC;
        const int kk = (t & 15) * DBK;
        GLD(zeh + (size_t)(row0 + w * 16 + srow) * C_DIM + kk + scol,
            &sA[b][0][(w * 16) * DBK]);
        GLD(zel + (size_t)(row0 + w * 16 + srow) * C_DIM + kk + scol,
            &sA[b][1][(w * 16) * DBK]);
        #pragma unroll
        for (int u = 0; u < 2; ++u) {
            const int rB = w * 32 + u * 16;
            GLD(cbh + (size_t)(col0 + rB + srow) * C_DIM + kk + scol,
                &sB[b][0][rB * DBK]);
            GLD(cbl + (size_t)(col0 + rB + srow) * C_DIM + kk + scol,
                &sB[b][1][rB * DBK]);
        }
    };

    __syncthreads();          // drain c2 LDS writes before pipeline starts
    stage(0, 0);
    stage(1, 1);

    int cur = 0;
    #pragma unroll 1
    for (int t = 0; t < NSTEPS; ++t) {
        if (t == NSTEPS - 1) {
            asm volatile("s_waitcnt vmcnt(0)" ::: "memory");
        } else {
            asm volatile("s_waitcnt vmcnt(6)" ::: "memory");  // stage(t) done
        }
        __builtin_amdgcn_s_barrier();

        bf16x8 ah[4], al[4], bh[4], bl[4];
        #pragma unroll
        for (int mi = 0; mi < 4; ++mi) {
            const int rowoff = (wr * 64 + mi * 16 + lr) * DBK + aslot;
            ah[mi] = *(const bf16x8*)&sA[cur][0][rowoff];
            al[mi] = *(const bf16x8*)&sA[cur][1][rowoff];
        }
        #pragma unroll
        for (int ni = 0; ni < 4; ++ni) {
            const int rowoff = (wc * 64 + ni * 16 + lr) * DBK + aslot;
            bh[ni] = *(const bf16x8*)&sB[cur][0][rowoff];
            bl[ni] = *(const bf16x8*)&sB[cur][1][rowoff];
        }

        if (t < NSTEPS - 2) {
            int nxt = cur + 2; if (nxt > 2) nxt -= 3;
            stage(t + 2, nxt);        // 6 loads fly across next barriers
        }

        __builtin_amdgcn_s_setprio(1);
        #pragma unroll
        for (int mi = 0; mi < 4; ++mi)
            #pragma unroll
            for (int ni = 0; ni < 4; ++ni)
                acc[mi][ni] = __builtin_amdgcn_mfma_f32_16x16x32_bf16(
                    ah[mi], bh[ni], acc[mi][ni], 0, 0, 0);
        #pragma unroll
        for (int mi = 0; mi < 4; ++mi)
            #pragma unroll
            for (int ni = 0; ni < 4; ++ni)
                acc[mi][ni] = __builtin_amdgcn_mfma_f32_16x16x32_bf16(
                    ah[mi], bl[ni], acc[mi][ni], 0, 0, 0);
        #pragma unroll
        for (int mi = 0; mi < 4; ++mi)
            #pragma unroll
            for (int ni = 0; ni < 4; ++ni)
                acc[mi][ni] = __builtin_amdgcn_mfma_f32_16x16x32_bf16(
                    al[mi], bh[ni], acc[mi][ni], 0, 0, 0);
        __builtin_amdgcn_s_setprio(0);

        if ((t & 15) == 15) {
            // chunk epilogue: d = c2 - 2*dot; codes ascend -> strict < = first
            const int col0 = (t >> 4) * DBNC;
            #pragma unroll
            for (int ni = 0; ni < 4; ++ni) {
                const int code = col0 + wc * 64 + ni * 16 + lr;
                const float c2v = c2_lds[code];
                #pragma unroll
                for (int mi = 0; mi < 4; ++mi)
                    #pragma unroll
                    for (int r = 0; r < 4; ++r) {
                        float d = fmaf(-2.f, acc[mi][ni][r], c2v);
                        if (d < rbv[mi][r]) { rbv[mi][r] = d; rbi[mi][r] = code; }
                    }
            }
            #pragma unroll
            for (int i = 0; i < 4; ++i)
                #pragma unroll
                for (int j = 0; j < 4; ++j) acc[i][j] = (f32x4)0.f;
        }

        cur = (cur == 2) ? 0 : cur + 1;
    }

    // reduce across the 16 lanes (lr) sharing each row
    #pragma unroll
    for (int off = 1; off < 16; off <<= 1) {
        #pragma unroll
        for (int mi = 0; mi < 4; ++mi)
            #pragma unroll
            for (int r = 0; r < 4; ++r) {
                float ov = __shfl_xor(rbv[mi][r], off);
                int   oi = __shfl_xor(rbi[mi][r], off);
                if (ov < rbv[mi][r] || (ov == rbv[mi][r] && oi < rbi[mi][r])) {
                    rbv[mi][r] = ov; rbi[mi][r] = oi;
                }
            }
    }

    __syncthreads();   // full drain; safe to overlay reduce scratch on sA
    float (*s_v)[4] = (float (*)[4])&sA[0][0][0];
    int   (*s_i)[4] = (int (*)[4])((char*)&sA[0][0][0] + DBM2 * 4 * 4);
    if (lr == 0) {
        #pragma unroll
        for (int mi = 0; mi < 4; ++mi)
            #pragma unroll
            for (int r = 0; r < 4; ++r) {
                int lrow = wr * 64 + mi * 16 + kg * 4 + r;
                s_v[lrow][wc] = rbv[mi][r];
                s_i[lrow][wc] = rbi[mi][r];
            }
    }
    __syncthreads();
    if (tid < DBM2) {
        float bv = s_v[tid][0]; int bi = s_i[tid][0];
        #pragma unroll
        for (int c = 1; c < 4; ++c) {
            float v = s_v[tid][c]; int i = s_i[tid][c];
            if (v < bv || (v == bv && i < bi)) { bv = v; bi = i; }
        }
        idx_out[row0 + tid] = (unsigned short)bi;
    }
}

// ---- per-stage update: lookup, residual (fp32->hi/lo), loss partial.
// quant_sum = x - final_residual -> only stage 7 writes out (saves ~1GB traffic)
__global__ __launch_bounds__(1024) void update_kernel(
    const int s, const float* __restrict__ x, const float* __restrict__ cb,
    const unsigned short* __restrict__ idx_sel, float* __restrict__ out,
    unsigned short* __restrict__ zeh, unsigned short* __restrict__ zel,
    float* __restrict__ rpart)
{
    __shared__ float swsum[16];
    const int wid = threadIdx.x >> 6, lane = threadIdx.x & 63;
    const int r = blockIdx.x * 16 + wid;
    const int bi = idx_sel[r];
    const size_t base = (size_t)r * C_DIM + lane * 8;
    const float* q = cb + (size_t)bi * C_DIM + lane * 8;

    float4 q0 = *(const float4*)q;
    float4 q1 = *(const float4*)(q + 4);
    float qq[8] = {q0.x, q0.y, q0.z, q0.w, q1.x, q1.y, q1.z, q1.w};

    float v[8];
    if (s == 0) {
        float4 z0 = *(const float4*)(x + base);
        float4 z1 = *(const float4*)(x + base + 4);
        v[0]=z0.x; v[1]=z0.y; v[2]=z0.z; v[3]=z0.w;
        v[4]=z1.x; v[5]=z1.y; v[6]=z1.z; v[7]=z1.w;
    } else {
        u16x8 h = *(const u16x8*)(zeh + base);
        u16x8 l = *(const u16x8*)(zel + base);
        #pragma unroll
        for (int j = 0; j < 8; ++j) v[j] = u2f(h[j]) + u2f(l[j]);
    }

    float rr[8];
    #pragma unroll
    for (int j = 0; j < 8; ++j) rr[j] = v[j] - qq[j];

    if (s < Q_STAGES - 1) {
        u16x8 hh, ll;
        #pragma unroll
        for (int j = 0; j < 8; ++j) {
            hh[j] = bf_hi_u(rr[j]);
            float lo = rr[j] - bf_hi_f(rr[j]);
            ll[j] = bf_hi_u(lo);
        }
        *(u16x8*)(zeh + base) = hh;
        *(u16x8*)(zel + base) = ll;
    } else {
        // quant_sum = x - final residual
        float4 x0 = *(const float4*)(x + base);
        float4 x1 = *(const float4*)(x + base + 4);
        float4 o0, o1;
        o0.x = x0.x - rr[0]; o0.y = x0.y - rr[1];
        o0.z = x0.z - rr[2]; o0.w = x0.w - rr[3];
        o1.x = x1.x - rr[4]; o1.y = x1.y - rr[5];
        o1.z = x1.z - rr[6]; o1.w = x1.w - rr[7];
        *(float4*)(out + base)     = o0;
        *(float4*)(out + base + 4) = o1;
    }

    float ssum = 0.f;
    #pragma unroll
    for (int j = 0; j < 8; ++j) ssum += rr[j] * rr[j];
    #pragma unroll
    for (int off = 1; off < 64; off <<= 1) ssum += __shfl_xor(ssum, off);
    if (lane == 0) swsum[wid] = ssum;
    __syncthreads();
    if (threadIdx.x == 0) {
        float t = 0.f;
        #pragma unroll
        for (int i = 0; i < 16; ++i) t += swsum[i];
        rpart[blockIdx.x] = t;
    }
}

__global__ __launch_bounds__(1024) void reduce2048_kernel(
    const float* __restrict__ rpart, float* __restrict__ slot)
{
    __shared__ float sm[1024];
    int t = threadIdx.x;
    sm[t] = rpart[t] + rpart[t + 1024];
    __syncthreads();
    for (int w2 = 512; w2 > 0; w2 >>= 1) {
        if (t < w2) sm[t] += sm[t + w2];
        __syncthreads();
    }
    if (t == 0) *slot = sm[0];
}

__global__ void finalize_kernel(const float* __restrict__ lossbuf,
                                float* __restrict__ out)
{
    if (threadIdx.x == 0) {
        float s = 0.f;
        #pragma unroll
        for (int i = 0; i < Q_STAGES; ++i) s += lossbuf[i];
        out[0] = 2.75f * s / (float)((size_t)N_ROWS * C_DIM);
    }
}

extern "C" void kernel_launch(void* const* d_in, const int* in_sizes, int n_in,
                              void* d_out, int out_size, void* d_ws, size_t ws_size,
                              hipStream_t stream)
{
    const float* x   = (const float*)d_in[0];   // [N, C]
    const float* cbs = (const float*)d_in[1];   // [Q, K, C]
    float* out = (float*)d_out;                 // [N*C] quant_sum, then 1 loss
    char* ws = (char*)d_ws;

    unsigned short* zeh = (unsigned short*)(ws + ZEH_OFF);
    unsigned short* zel = (unsigned short*)(ws + ZEL_OFF);
    unsigned short* cbh = (unsigned short*)(ws + CBH_OFF);
    unsigned short* cbl = (unsigned short*)(ws + CBL_OFF);
    float* c2    = (float*)(ws + C2_OFF);
    unsigned short* gidx = (unsigned short*)(ws + IDX_OFF);
    float* rpart = (float*)(ws + RPT_OFF);
    float* lossb = (float*)(ws + LSB_OFF);

    // x -> hi/lo bf16; codebook norms (fp32 exact)
    split_kernel<<<(N_ROWS * C_DIM / 4 + 255) / 256, 256, 0, stream>>>(
        x, zeh, zel, N_ROWS * C_DIM / 4);
    rowsq_kernel<<<(Q_STAGES * K_CODES * 64) / 256, 256, 0, stream>>>(
        cbs, c2, Q_STAGES * K_CODES);

    for (int s = 0; s < Q_STAGES; ++s) {
        const float* cb = cbs + (size_t)s * K_CODES * C_DIM;
        split_kernel<<<(K_CODES * C_DIM / 4 + 255) / 256, 256, 0, stream>>>(
            cb, cbh, cbl, K_CODES * C_DIM / 4);
        dist_kernel<<<N_ROWS / DBM2, 512, 0, stream>>>(
            zeh, zel, cbh, cbl, c2 + (size_t)s * K_CODES, gidx);
        update_kernel<<<N_ROWS / 16, 1024, 0, stream>>>(
            s, x, cb, gidx, out, zeh, zel, rpart);
        reduce2048_kernel<<<1, 1024, 0, stream>>>(rpart, lossb + s);
    }
    finalize_kernel<<<1, 64, 0, stream>>>(lossb, out + (size_t)N_ROWS * C_DIM);
}